// Round 10
// baseline (610.519 us; speedup 1.0000x reference)
//
#include <hip/hip_runtime.h>
#include <stdint.h>

#define HW    480
#define KS    24
#define CH    3
#define HO    457            // 480-24+1
#define NPOS  (HO*HO)        // 208849
#define NP    400
#define PS    (CH*KS*KS)     // 1728
#define SIG   1e-6f
#define NST   108            // exact K16 steps: 1728/16
#define NMT   15             // 32-patch MFMA tiles (480 padded patches, /3 groups)
#define NIY   115            // ceil(457/4) row-quads
#define NGRP  (NIY*8*4)      // 3680: (iy,jx,row-in-quad) coarse groups (64 j each)
#define MAXF  16384
#define DELTA 3e-3f          // ~68 sigma of coarse bf16 corr error
#define SPLN  2608           // LDS plane stride (27*96 rounded +16 for bank spread)

typedef __attribute__((ext_vector_type(8))) short short8;
typedef __attribute__((ext_vector_type(16))) float float16v;
typedef unsigned int uint;
typedef unsigned short ushort;
typedef unsigned long long ull;

static __device__ __forceinline__ ushort f2bf(float v) {
    uint u = __float_as_uint(v);
    uint r = (u + 0x7fffu + ((u >> 16) & 1u)) >> 16;   // RNE
    return (ushort)r;
}
static __device__ __forceinline__ uint mono(float f) {      // order-preserving f32->u32
    uint u = __float_as_uint(f);
    return (u & 0x80000000u) ? ~u : (u | 0x80000000u);
}
static __device__ __forceinline__ float unmono(uint u) {
    uint b = (u & 0x80000000u) ? (u & 0x7fffffffu) : ~u;
    return __uint_as_float(b);
}
static __device__ __forceinline__ uint fsh(uint x, uint y) { // shift by 1 ushort
    return (x >> 16) | (y << 16);
}

// ---------------- prep kernels ----------------

__global__ void repack_k(const float* __restrict__ x, float* __restrict__ Wp) {
    int t = blockIdx.x * 256 + threadIdx.x;
    if (t >= NP * PS) return;
    int p = t / PS, e = t - p * PS;
    int c = e / (KS * KS);
    int r = (e / KS) % KS;
    int w = e % KS;
    int pr = p / 20, pc = p - pr * 20;
    Wp[t] = x[c * HW * HW + (pr * KS + r) * HW + (pc * KS + w)];
}

__global__ void stats_k(const float* __restrict__ Wp,
                        float* __restrict__ meanX, float* __restrict__ denXa) {
    __shared__ float shs[4], shs2[4];
    int p = blockIdx.x;
    float s = 0.f, s2 = 0.f;
    for (int e = threadIdx.x; e < PS; e += 256) {
        float v = Wp[p * PS + e];
        s += v; s2 += v * v;
    }
    for (int o = 32; o > 0; o >>= 1) { s += __shfl_down(s, o); s2 += __shfl_down(s2, o); }
    int lane = threadIdx.x & 63, wv = threadIdx.x >> 6;
    if (lane == 0) { shs[wv] = s; shs2[wv] = s2; }
    __syncthreads();
    if (threadIdx.x == 0) {
        float S = shs[0] + shs[1] + shs[2] + shs[3];
        float S2 = shs2[0] + shs2[1] + shs2[2] + shs2[3];
        float m = S / (float)PS;
        meanX[p] = m;
        denXa[p] = fabsf(S2 / (float)PS - m * m);
    }
}

// y_dec -> bf16 hi plane (coarse path)
__global__ void ybf_k(const float* __restrict__ y, ushort* __restrict__ yb) {
    int t = blockIdx.x * 256 + threadIdx.x;
    if (t >= CH * HW * HW) return;
    yb[t] = f2bf(y[t]);
}

// Pack A hi fragments (exact K, unshifted): frag f = mtg*108 + s, 512 bf16/frag.
// A[m][k]: m = lane&31, k = (lane>>5)*8 + e, kk = 16s + k (flat [c][kh][kw]).
__global__ void packAh_k(const float* __restrict__ Wp, ushort* __restrict__ Ap) {
    int id = blockIdx.x * 256 + threadIdx.x;
    if (id >= NMT * NST * 512) return;
    int e = id & 7;
    int L = (id >> 3) & 63;
    int f = id >> 9;
    int s = f % NST;
    int mtg = f / NST;
    int kk = s * 16 + (L >> 5) * 8 + e;
    int p = mtg * 32 + (L & 31);
    float v = (p < NP) ? Wp[p * PS + kk] : 0.f;
    Ap[id] = f2bf(v);
}

__global__ void colsum_k(const float* __restrict__ y,
                         float* __restrict__ cs, float* __restrict__ cs2) {
    int t = blockIdx.x * 256 + threadIdx.x;
    if (t >= HO * HW) return;
    int i = t / HW, w = t - i * HW;
    float s = 0.f, s2 = 0.f;
    for (int c = 0; c < CH; c++) {
        const float* base = y + c * HW * HW + i * HW + w;
        for (int dh = 0; dh < KS; dh++) {
            float v = base[dh * HW];
            s += v; s2 += v * v;
        }
    }
    cs[t] = s; cs2[t] = s2;
}

__global__ void window_k(const float* __restrict__ cs, const float* __restrict__ cs2,
                         float* __restrict__ sumY, float* __restrict__ denYa) {
    int t = blockIdx.x * 256 + threadIdx.x;
    if (t >= NPOS) return;
    int i = t / HO, j = t - i * HO;
    const float* r  = cs  + i * HW + j;
    const float* r2 = cs2 + i * HW + j;
    float s = 0.f, s2 = 0.f;
    for (int d = 0; d < KS; d++) { s += r[d]; s2 += r2[d]; }
    sumY[t] = s;
    float ips = 1.0f / (float)PS;
    denYa[t] = fabsf(s2 * ips - (s * ips) * (s * ips));
}

// ---------------- phase1: coarse bf16-hi correlation, per-group max ----------------
// grid(8=jx, 115=iy, 5=mtp). Block 256 = 4 waves; wave g = output row i0+g.
// Wave: 96 patches (mt3) x 64 positions (j = 64*jx + 2n + t) x 1 row.
// B in 4 LDS planes shifted by 0..3 ushorts: lane n, shift t reads plane
// (2n+t)&3 at even-uint base (2n)&~3 -> every frag = 2 aligned ds_read_b64,
// same offsets for t=0/1. acc[mt3][t2] = 96 AGPR -> 3 waves/SIMD.
__launch_bounds__(256, 3)
__global__ void corr1_k(const ushort* __restrict__ ybf, const ushort* __restrict__ Ap,
                        const float* __restrict__ meanX, const float* __restrict__ denXa,
                        const float* __restrict__ sumY, const float* __restrict__ denYa,
                        uint* __restrict__ table) {
    __shared__ ushort S[4 * SPLN];   // 20864 B

    const int tid  = threadIdx.x;
    const int lane = tid & 63;
    const int g    = tid >> 6;      // wave = row within quad
    const int n    = lane & 31;
    const int kha  = lane >> 5;
    const int jx   = blockIdx.x;
    const int iy   = blockIdx.y;
    const int mtp  = blockIdx.z;
    const int j0   = 64 * jx;
    const int i0   = 4 * iy;
    const int i    = i0 + g;

    // per-(u,kha) in-plane ushort offsets (row stride 96); all == 0 mod 8
    const int off0 = kha ? 8  : 0;
    const int off1 = kha ? 96 : 16;
    const int off2 = kha ? 112 : 104;

    const ushort* B0p = S + ((n & 1) * 2)     * SPLN + 4 * (n >> 1);
    const ushort* B1p = S + ((n & 1) * 2 + 1) * SPLN + 4 * (n >> 1);

    const ushort* A0 = Ap + ((size_t)(mtp * 3 + 0) * NST) * 512 + lane * 8;
    const ushort* A1 = Ap + ((size_t)(mtp * 3 + 1) * NST) * 512 + lane * 8;
    const ushort* A2 = Ap + ((size_t)(mtp * 3 + 2) * NST) * 512 + lane * 8;

    float16v acc[3][2];   // [mt][t]
#pragma unroll
    for (int mt = 0; mt < 3; mt++)
#pragma unroll
        for (int t = 0; t < 2; t++) acc[mt][t] = (float16v)0.f;

    for (int c = 0; c < CH; c++) {
        __syncthreads();
        // stage 27 rows x 96 cols into 4 shift-planes
        for (int it = tid; it < 27 * 12; it += 256) {
            int row = it / 12;
            int g8  = (it - row * 12) * 8;
            int yr  = i0 + row;
            int gj  = j0 + g8;
            uint a0 = 0, a1 = 0, a2 = 0, a3 = 0, b0 = 0, b1 = 0;
            if (yr < HW) {
                const ushort* src = ybf + (c * HW + yr) * HW;
                if (gj + 12 <= HW) {
                    uint4 a = *(const uint4*)(src + gj);      // 16B-aligned (gj%8==0)
                    uint2 b = *(const uint2*)(src + gj + 8);
                    a0 = a.x; a1 = a.y; a2 = a.z; a3 = a.w; b0 = b.x; b1 = b.y;
                } else {
                    ushort tmp[12];
#pragma unroll
                    for (int e = 0; e < 12; e++) tmp[e] = (gj + e < HW) ? src[gj + e] : (ushort)0;
                    const uint* tp = (const uint*)tmp;
                    a0 = tp[0]; a1 = tp[1]; a2 = tp[2]; a3 = tp[3]; b0 = tp[4]; b1 = tp[5];
                }
            }
            int base = row * 96 + g8;
            *(uint4*)&S[0 * SPLN + base] = make_uint4(a0, a1, a2, a3);
            *(uint4*)&S[1 * SPLN + base] = make_uint4(fsh(a0, a1), fsh(a1, a2), fsh(a2, a3), fsh(a3, b0));
            *(uint4*)&S[2 * SPLN + base] = make_uint4(a1, a2, a3, b0);
            *(uint4*)&S[3 * SPLN + base] = make_uint4(fsh(a1, a2), fsh(a2, a3), fsh(a3, b0), fsh(b0, b1));
        }
        __syncthreads();

        for (int q = 0; q < 12; q++) {
            const int ro = (2 * q + g) * 96;
#pragma unroll
            for (int u = 0; u < 3; u++) {
                const int s = c * 36 + 3 * q + u;
                short8 a0 = *(const short8*)(A0 + ((size_t)s << 9));
                short8 a1 = *(const short8*)(A1 + ((size_t)s << 9));
                short8 a2 = *(const short8*)(A2 + ((size_t)s << 9));
                const int o = ro + ((u == 0) ? off0 : (u == 1) ? off1 : off2);
                union { uint2 d[2]; short8 v; } b0, b1;
                b0.d[0] = *(const uint2*)(B0p + o);
                b0.d[1] = *(const uint2*)(B0p + o + 4);
                b1.d[0] = *(const uint2*)(B1p + o);
                b1.d[1] = *(const uint2*)(B1p + o + 4);
                acc[0][0] = __builtin_amdgcn_mfma_f32_32x32x16_bf16(a0, b0.v, acc[0][0], 0, 0, 0);
                acc[0][1] = __builtin_amdgcn_mfma_f32_32x32x16_bf16(a0, b1.v, acc[0][1], 0, 0, 0);
                acc[1][0] = __builtin_amdgcn_mfma_f32_32x32x16_bf16(a1, b0.v, acc[1][0], 0, 0, 0);
                acc[1][1] = __builtin_amdgcn_mfma_f32_32x32x16_bf16(a1, b1.v, acc[1][1], 0, 0, 0);
                acc[2][0] = __builtin_amdgcn_mfma_f32_32x32x16_bf16(a2, b0.v, acc[2][0], 0, 0, 0);
                acc[2][1] = __builtin_amdgcn_mfma_f32_32x32x16_bf16(a2, b1.v, acc[2][1], 0, 0, 0);
            }
        }
    }

    // ---- epilogue: coarse corr, per-(patch, group) max ----
    const int grp = (iy * 8 + jx) * 4 + g;
    const float invps = 1.0f / (float)PS;
    const bool iok = i < HO;
    float sYv[2], dYv[2];
#pragma unroll
    for (int t = 0; t < 2; t++) {
        int j = j0 + 2 * n + t;
        bool ok = iok && (j < HO);
        sYv[t] = ok ? sumY[i * HO + j] : 0.f;
        dYv[t] = ok ? denYa[i * HO + j] : 0.f;
    }
#pragma unroll
    for (int mt = 0; mt < 3; mt++) {
        const int pbase = (mtp * 3 + mt) * 32;
#pragma unroll
        for (int r = 0; r < 16; r++) {
            int p = pbase + (r & 3) + 8 * (r >> 2) + 4 * kha;
            bool pok = p < NP;
            float mX = pok ? meanX[p] : 0.f;
            float dX = pok ? denXa[p] : 0.f;
            uint bu = 0;
#pragma unroll
            for (int t = 0; t < 2; t++) {
                int j = j0 + 2 * n + t;
                if (iok && j < HO) {
                    float corr = (2.0f * (acc[mt][t][r] - mX * sYv[t]) * invps + SIG)
                               / (dX + dYv[t] + SIG);
                    uint uu = mono(corr);
                    bu = uu > bu ? uu : bu;
                }
            }
#pragma unroll
            for (int o = 1; o < 32; o <<= 1) {
                uint other = __shfl_xor(bu, o);
                bu = other > bu ? other : bu;
            }
            if (n == 0 && pok) table[p * NGRP + grp] = bu;
        }
    }
}

// ---------------- phase2a: per-patch threshold + flagged-group emission ----------------
__global__ void flag_k(const uint* __restrict__ table,
                       uint* __restrict__ flags, uint* __restrict__ cnt) {
    __shared__ uint sm[4];
    __shared__ float sthr;
    int p = blockIdx.x;
    uint m = 0;
    for (int g = threadIdx.x; g < NGRP; g += 256) {
        uint v = table[p * NGRP + g];
        m = v > m ? v : m;
    }
    for (int o = 32; o > 0; o >>= 1) { uint ot = __shfl_down(m, o); m = ot > m ? ot : m; }
    int lane = threadIdx.x & 63, wv = threadIdx.x >> 6;
    if (lane == 0) sm[wv] = m;
    __syncthreads();
    if (threadIdx.x == 0) {
        uint mm = max(max(sm[0], sm[1]), max(sm[2], sm[3]));
        sthr = unmono(mm) - DELTA;
    }
    __syncthreads();
    float thr = sthr;
    for (int g = threadIdx.x; g < NGRP; g += 256) {
        if (unmono(table[p * NGRP + g]) >= thr) {
            uint idx = atomicAdd(cnt, 1u);
            if (idx < MAXF) flags[idx] = (uint)(p * NGRP + g);
        }
    }
}

// ---------------- phase2b: exact fp32 rescoring of flagged groups ----------------
// One wave per flag; group = 1 row x 64 j.
__launch_bounds__(64)
__global__ void rescore_k(const float* __restrict__ Wp, const float* __restrict__ y_dec,
                          const float* __restrict__ meanX, const float* __restrict__ denXa,
                          const float* __restrict__ sumY, const float* __restrict__ denYa,
                          const uint* __restrict__ flags, const uint* __restrict__ cnt,
                          ull* __restrict__ best) {
    uint nflag = *cnt; if (nflag > MAXF) nflag = MAXF;
    if (blockIdx.x >= nflag) return;
    uint f = flags[blockIdx.x];
    int p = f / NGRP, grp = f - p * NGRP;
    int g = grp & 3, bj = grp >> 2;
    int jx = bj & 7, iy = bj >> 3;
    int i = 4 * iy + g;
    int j = 64 * jx + threadIdx.x;
    ull pk = 0;
    if (i < HO && j < HO) {
        float dot = 0.f;
        const float* wr = Wp + p * PS;
        for (int c = 0; c < CH; c++)
            for (int kh = 0; kh < KS; kh++) {
                const float* yr = y_dec + ((c * HW) + i + kh) * HW + j;
                const float* wk = wr + (c * KS + kh) * KS;
#pragma unroll
                for (int kw = 0; kw < KS; kw++) dot += wk[kw] * yr[kw];
            }
        float corr = (2.0f * (dot - meanX[p] * sumY[i * HO + j]) * (1.0f / (float)PS) + SIG)
                   / (denXa[p] + denYa[i * HO + j] + SIG);
        uint idx = (uint)(i * HO + j);
        pk = ((ull)mono(corr) << 32) | (uint)(~idx);   // first-max tie-break via ~idx
    }
    for (int o = 32; o > 0; o >>= 1) { ull ot = __shfl_down(pk, o); pk = ot > pk ? ot : pk; }
    if (threadIdx.x == 0) atomicMax(&best[p], pk);
}

// ---------------- gather ----------------
__global__ void gather_k(const float* __restrict__ y,
                         const ull* __restrict__ best,
                         float* __restrict__ out) {
    int p = blockIdx.x;
    uint idx = ~((uint)(best[p] & 0xFFFFFFFFull));
    int r = idx / HO, cc = idx - r * HO;
    int pr = p / 20, pc = p - pr * 20;
    for (int e = threadIdx.x; e < PS; e += 256) {
        int c = e / (KS * KS);
        int kh = (e / KS) % KS;
        int kw = e % KS;
        out[c * HW * HW + (pr * KS + kh) * HW + (pc * KS + kw)] =
            y[c * HW * HW + (r + kh) * HW + (cc + kw)];
    }
}

// ---------------- launch ----------------
extern "C" void kernel_launch(void* const* d_in, const int* in_sizes, int n_in,
                              void* d_out, int out_size, void* d_ws, size_t ws_size,
                              hipStream_t stream) {
    const float* x_dec = (const float*)d_in[0];
    const float* y_dec = (const float*)d_in[1];
    const float* y     = (const float*)d_in[2];
    float* out = (float*)d_out;

    char* ws = (char*)d_ws;
    size_t off = 0;
    auto carve = [&](size_t bytes) -> void* {
        void* p = ws + off;
        off += (bytes + 255) & ~(size_t)255;
        return p;
    };
    float*  Wp    = (float*)carve((size_t)NP * PS * 4);           // 2.77 MB
    ushort* ybf   = (ushort*)carve((size_t)CH * HW * HW * 2);     // 1.38 MB
    ushort* Ap    = (ushort*)carve((size_t)NMT * NST * 512 * 2);  // 1.66 MB
    float*  cs    = (float*)carve((size_t)HO * HW * 4);
    float*  cs2   = (float*)carve((size_t)HO * HW * 4);
    float*  sumY  = (float*)carve((size_t)NPOS * 4);
    float*  denYa = (float*)carve((size_t)NPOS * 4);
    float*  meanX = (float*)carve((size_t)NP * 4);
    float*  denXa = (float*)carve((size_t)NP * 4);
    uint*   table = (uint*)carve((size_t)NP * NGRP * 4);          // 5.89 MB
    uint*   flags = (uint*)carve((size_t)MAXF * 4);
    uint*   cnt   = (uint*)carve(256);
    ull*    best  = (ull*)carve((size_t)NP * 8);

    hipMemsetAsync(cnt, 0, 4, stream);
    hipMemsetAsync(best, 0, (size_t)NP * 8, stream);

    repack_k<<<(NP * PS + 255) / 256, 256, 0, stream>>>(x_dec, Wp);
    stats_k<<<NP, 256, 0, stream>>>(Wp, meanX, denXa);
    ybf_k<<<(CH * HW * HW + 255) / 256, 256, 0, stream>>>(y_dec, ybf);
    packAh_k<<<(NMT * NST * 512 + 255) / 256, 256, 0, stream>>>(Wp, Ap);
    colsum_k<<<(HO * HW + 255) / 256, 256, 0, stream>>>(y_dec, cs, cs2);
    window_k<<<(NPOS + 255) / 256, 256, 0, stream>>>(cs, cs2, sumY, denYa);

    dim3 grid(8, NIY, 5);
    corr1_k<<<grid, 256, 0, stream>>>(ybf, Ap, meanX, denXa, sumY, denYa, table);

    flag_k<<<NP, 256, 0, stream>>>(table, flags, cnt);
    rescore_k<<<MAXF, 64, 0, stream>>>(Wp, y_dec, meanX, denXa, sumY, denYa, flags, cnt, best);

    gather_k<<<NP, 256, 0, stream>>>(y, best, out);
}

// Round 11
// 535.033 us; speedup vs baseline: 1.1411x; 1.1411x over previous
//
#include <hip/hip_runtime.h>
#include <stdint.h>

#define HW    480
#define KS    24
#define CH    3
#define HO    457            // 480-24+1
#define NPOS  (HO*HO)        // 208849
#define NP    400
#define PS    (CH*KS*KS)     // 1728
#define SIG   1e-6f
#define NST   108            // exact K16 steps: 1728/16
#define NMT   14             // 32-patch MFMA tiles (448 padded patches)
#define NIY   115            // ceil(457/4) row-quads
#define NGRP  (NIY*8*4)      // 3680: (iy,jx,row-in-quad) coarse groups (64 j each)
#define MAXF  16384
#define DELTA 3e-3f          // ~68 sigma of coarse bf16 corr error

typedef __attribute__((ext_vector_type(8))) short short8;
typedef __attribute__((ext_vector_type(16))) float float16v;
typedef unsigned int uint;
typedef unsigned short ushort;
typedef unsigned long long ull;

static __device__ __forceinline__ ushort f2bf(float v) {
    uint u = __float_as_uint(v);
    uint r = (u + 0x7fffu + ((u >> 16) & 1u)) >> 16;   // RNE
    return (ushort)r;
}
static __device__ __forceinline__ uint mono(float f) {      // order-preserving f32->u32
    uint u = __float_as_uint(f);
    return (u & 0x80000000u) ? ~u : (u | 0x80000000u);
}
static __device__ __forceinline__ float unmono(uint u) {
    uint b = (u & 0x80000000u) ? (u & 0x7fffffffu) : ~u;
    return __uint_as_float(b);
}
static __device__ __forceinline__ uint fsh(uint x, uint y) { // shift by 1 ushort
    return (x >> 16) | (y << 16);
}

// ---------------- fat prep kernel 1: repack + ybf + colsum ----------------
// (all read only the raw inputs; fused to cut launch overhead)
__global__ void fat1_k(const float* __restrict__ x, const float* __restrict__ yd,
                       float* __restrict__ Wp, ushort* __restrict__ yb,
                       float* __restrict__ cs, float* __restrict__ cs2) {
    int b = blockIdx.x;
    if (b < 2700) {                       // repack: x_dec patches -> Wp[p][c][kh][kw]
        int t = b * 256 + threadIdx.x;    // 2700*256 == NP*PS exactly
        int p = t / PS, e = t - p * PS;
        int c = e / (KS * KS);
        int r = (e / KS) % KS;
        int w = e % KS;
        int pr = p / 20, pc = p - pr * 20;
        Wp[t] = x[c * HW * HW + (pr * KS + r) * HW + (pc * KS + w)];
    } else if (b < 5400) {                // ybf: y_dec -> bf16 hi plane
        int t = (b - 2700) * 256 + threadIdx.x;
        yb[t] = f2bf(yd[t]);
    } else {                              // colsum: vertical 24-row sums
        int t = (b - 5400) * 256 + threadIdx.x;
        if (t >= HO * HW) return;
        int i = t / HW, w = t - i * HW;
        float s = 0.f, s2 = 0.f;
        for (int c = 0; c < CH; c++) {
            const float* base = yd + c * HW * HW + i * HW + w;
            for (int dh = 0; dh < KS; dh++) {
                float v = base[dh * HW];
                s += v; s2 += v * v;
            }
        }
        cs[t] = s; cs2[t] = s2;
    }
}

// ---------------- fat prep kernel 2: stats + packAh + window + init ----------------
__global__ void fat2_k(const float* __restrict__ Wp,
                       const float* __restrict__ cs, const float* __restrict__ cs2,
                       float* __restrict__ meanX, float* __restrict__ denXa,
                       ushort* __restrict__ Ap,
                       float* __restrict__ sumY, float* __restrict__ denYa,
                       uint* __restrict__ cnt, ull* __restrict__ best) {
    __shared__ float shs[4], shs2[4];
    int b = blockIdx.x;
    if (b < 400) {                        // stats for patch b (+ init best/cnt)
        int p = b;
        if (threadIdx.x == 1) best[p] = 0ull;
        if (b == 0 && threadIdx.x == 2) *cnt = 0u;
        float s = 0.f, s2 = 0.f;
        for (int e = threadIdx.x; e < PS; e += 256) {
            float v = Wp[p * PS + e];
            s += v; s2 += v * v;
        }
        for (int o = 32; o > 0; o >>= 1) { s += __shfl_down(s, o); s2 += __shfl_down(s2, o); }
        int lane = threadIdx.x & 63, wv = threadIdx.x >> 6;
        if (lane == 0) { shs[wv] = s; shs2[wv] = s2; }
        __syncthreads();
        if (threadIdx.x == 0) {
            float S = shs[0] + shs[1] + shs[2] + shs[3];
            float S2 = shs2[0] + shs2[1] + shs2[2] + shs2[3];
            float m = S / (float)PS;
            meanX[p] = m;
            denXa[p] = fabsf(S2 / (float)PS - m * m);
        }
    } else if (b < 3424) {                // packAh: A hi fragments, exact K
        int id = (b - 400) * 256 + threadIdx.x;   // 3024*256 == NMT*NST*512 exactly
        int e = id & 7;
        int L = (id >> 3) & 63;
        int f = id >> 9;
        int s = f % NST;
        int mtg = f / NST;
        int kk = s * 16 + (L >> 5) * 8 + e;
        int p = mtg * 32 + (L & 31);
        float v = (p < NP) ? Wp[p * PS + kk] : 0.f;
        Ap[id] = f2bf(v);
    } else {                              // window: horizontal 24-col sums
        int t = (b - 3424) * 256 + threadIdx.x;
        if (t >= NPOS) return;
        int i = t / HO, j = t - i * HO;
        const float* r  = cs  + i * HW + j;
        const float* r2 = cs2 + i * HW + j;
        float s = 0.f, s2 = 0.f;
        for (int d = 0; d < KS; d++) { s += r[d]; s2 += r2[d]; }
        sumY[t] = s;
        float ips = 1.0f / (float)PS;
        denYa[t] = fabsf(s2 * ips - (s * ips) * (s * ips));
    }
}

// ---------------- phase1: coarse bf16-hi correlation, per-group max ----------------
// R9 structure verbatim (verified 435 us @ 3 waves/SIMD) with two deltas:
//  - __launch_bounds__(256,4): VGPR64+AGPR64 = 128 fits 4 waves/SIMD exactly
//  - staging width 160 -> 96 cols (only 88 are read; pattern verified in R10)
// grid(8=jx, 115=iy, 7=mtp). Wave g = output row i0+g; 64 patches (mt2) x
// 64 positions (j = 64*jx + 2n + t) x 1 row. t absorbed via one-ushort-shifted
// second LDS plane; B-frag = 8 direct uint reads (conflict-free).
__launch_bounds__(256, 4)
__global__ void corr1_k(const ushort* __restrict__ ybf, const ushort* __restrict__ Ap,
                        const float* __restrict__ meanX, const float* __restrict__ denXa,
                        const float* __restrict__ sumY, const float* __restrict__ denYa,
                        uint* __restrict__ table) {
    __shared__ ushort P0[27 * 96];   // hi plane
    __shared__ ushort P1[27 * 96];   // hi plane shifted by +1 ushort (t=1)

    const int tid  = threadIdx.x;
    const int lane = tid & 63;
    const int g    = tid >> 6;      // wave = row within quad
    const int n    = lane & 31;
    const int kha  = lane >> 5;
    const int jx   = blockIdx.x;
    const int iy   = blockIdx.y;
    const int mtp  = blockIdx.z;
    const int j0   = 64 * jx;
    const int i0   = 4 * iy;
    const int i    = i0 + g;

    // per-(u,kha) LDS offsets (row stride 96)
    const int off0 = kha ? 8   : 0;
    const int off1 = kha ? 96  : 16;
    const int off2 = kha ? 112 : 104;

    const ushort* A0 = Ap + ((size_t)(mtp * 2 + 0) * NST) * 512 + lane * 8;
    const ushort* A1 = Ap + ((size_t)(mtp * 2 + 1) * NST) * 512 + lane * 8;

    float16v acc[2][2];   // [mt][t]
#pragma unroll
    for (int mt = 0; mt < 2; mt++)
#pragma unroll
        for (int t = 0; t < 2; t++) acc[mt][t] = (float16v)0.f;

    for (int c = 0; c < CH; c++) {
        __syncthreads();
        // stage 27 rows x 96 cols: P0 = y rows, P1 = shifted by one pixel
        for (int it = tid; it < 27 * 12; it += 256) {
            int row = it / 12;
            int g8  = (it - row * 12) * 8;
            int yr  = i0 + row;
            int gj  = j0 + g8;
            uint a0 = 0, a1 = 0, a2 = 0, a3 = 0, e8 = 0;
            if (yr < HW) {
                const ushort* src = ybf + (c * HW + yr) * HW;
                if (gj + 9 <= HW) {
                    uint4 a = *(const uint4*)(src + gj);     // 16B-aligned (gj%8==0)
                    a0 = a.x; a1 = a.y; a2 = a.z; a3 = a.w;
                    e8 = src[gj + 8];
                } else {
                    ushort tmp[8];
#pragma unroll
                    for (int e = 0; e < 8; e++) tmp[e] = (gj + e < HW) ? src[gj + e] : (ushort)0;
                    const uint* tp = (const uint*)tmp;
                    a0 = tp[0]; a1 = tp[1]; a2 = tp[2]; a3 = tp[3];
                    e8 = 0;
                }
            }
            int base = row * 96 + g8;
            *(uint4*)&P0[base] = make_uint4(a0, a1, a2, a3);
            *(uint4*)&P1[base] = make_uint4(fsh(a0, a1), fsh(a1, a2), fsh(a2, a3), fsh(a3, e8));
        }
        __syncthreads();

        for (int q = 0; q < 12; q++) {
            const int rbase = (2 * q + g) * 96 + 2 * n;
#pragma unroll
            for (int u = 0; u < 3; u++) {
                const int s = c * 36 + 3 * q + u;
                short8 ah0 = *(const short8*)(A0 + ((size_t)s << 9));
                short8 ah1 = *(const short8*)(A1 + ((size_t)s << 9));
                const int idx = rbase + ((u == 0) ? off0 : (u == 1) ? off1 : off2);
                union { uint u4[4]; short8 v; } b0, b1;
                const uint* p0 = (const uint*)(P0 + idx);
                const uint* p1 = (const uint*)(P1 + idx);
#pragma unroll
                for (int w = 0; w < 4; w++) { b0.u4[w] = p0[w]; b1.u4[w] = p1[w]; }
                acc[0][0] = __builtin_amdgcn_mfma_f32_32x32x16_bf16(ah0, b0.v, acc[0][0], 0, 0, 0);
                acc[0][1] = __builtin_amdgcn_mfma_f32_32x32x16_bf16(ah0, b1.v, acc[0][1], 0, 0, 0);
                acc[1][0] = __builtin_amdgcn_mfma_f32_32x32x16_bf16(ah1, b0.v, acc[1][0], 0, 0, 0);
                acc[1][1] = __builtin_amdgcn_mfma_f32_32x32x16_bf16(ah1, b1.v, acc[1][1], 0, 0, 0);
            }
        }
    }

    // ---- epilogue: coarse corr, per-(patch, group) max ----
    const int grp = (iy * 8 + jx) * 4 + g;
    const float invps = 1.0f / (float)PS;
    const bool iok = i < HO;
    float sYv[2], dYv[2];
#pragma unroll
    for (int t = 0; t < 2; t++) {
        int j = j0 + 2 * n + t;
        bool ok = iok && (j < HO);
        sYv[t] = ok ? sumY[i * HO + j] : 0.f;
        dYv[t] = ok ? denYa[i * HO + j] : 0.f;
    }
#pragma unroll
    for (int mt = 0; mt < 2; mt++) {
        const int pbase = (mtp * 2 + mt) * 32;
#pragma unroll
        for (int r = 0; r < 16; r++) {
            int p = pbase + (r & 3) + 8 * (r >> 2) + 4 * kha;
            bool pok = p < NP;
            float mX = pok ? meanX[p] : 0.f;
            float dX = pok ? denXa[p] : 0.f;
            uint bu = 0;
#pragma unroll
            for (int t = 0; t < 2; t++) {
                int j = j0 + 2 * n + t;
                if (iok && j < HO) {
                    float corr = (2.0f * (acc[mt][t][r] - mX * sYv[t]) * invps + SIG)
                               / (dX + dYv[t] + SIG);
                    uint uu = mono(corr);
                    bu = uu > bu ? uu : bu;
                }
            }
#pragma unroll
            for (int o = 1; o < 32; o <<= 1) {
                uint other = __shfl_xor(bu, o);
                bu = other > bu ? other : bu;
            }
            if (n == 0 && pok) table[p * NGRP + grp] = bu;
        }
    }
}

// ---------------- phase2a: per-patch threshold + flagged-group emission ----------------
__global__ void flag_k(const uint* __restrict__ table,
                       uint* __restrict__ flags, uint* __restrict__ cnt) {
    __shared__ uint sm[4];
    __shared__ float sthr;
    int p = blockIdx.x;
    uint m = 0;
    for (int g = threadIdx.x; g < NGRP; g += 256) {
        uint v = table[p * NGRP + g];
        m = v > m ? v : m;
    }
    for (int o = 32; o > 0; o >>= 1) { uint ot = __shfl_down(m, o); m = ot > m ? ot : m; }
    int lane = threadIdx.x & 63, wv = threadIdx.x >> 6;
    if (lane == 0) sm[wv] = m;
    __syncthreads();
    if (threadIdx.x == 0) {
        uint mm = max(max(sm[0], sm[1]), max(sm[2], sm[3]));
        sthr = unmono(mm) - DELTA;
    }
    __syncthreads();
    float thr = sthr;
    for (int g = threadIdx.x; g < NGRP; g += 256) {
        if (unmono(table[p * NGRP + g]) >= thr) {
            uint idx = atomicAdd(cnt, 1u);
            if (idx < MAXF) flags[idx] = (uint)(p * NGRP + g);
        }
    }
}

// ---------------- phase2b: exact fp32 rescoring of flagged groups ----------------
// One wave per flag; group = 1 row x 64 j.
__launch_bounds__(64)
__global__ void rescore_k(const float* __restrict__ Wp, const float* __restrict__ y_dec,
                          const float* __restrict__ meanX, const float* __restrict__ denXa,
                          const float* __restrict__ sumY, const float* __restrict__ denYa,
                          const uint* __restrict__ flags, const uint* __restrict__ cnt,
                          ull* __restrict__ best) {
    uint nflag = *cnt; if (nflag > MAXF) nflag = MAXF;
    if (blockIdx.x >= nflag) return;
    uint f = flags[blockIdx.x];
    int p = f / NGRP, grp = f - p * NGRP;
    int g = grp & 3, bj = grp >> 2;
    int jx = bj & 7, iy = bj >> 3;
    int i = 4 * iy + g;
    int j = 64 * jx + threadIdx.x;
    ull pk = 0;
    if (i < HO && j < HO) {
        float dot = 0.f;
        const float* wr = Wp + p * PS;
        for (int c = 0; c < CH; c++)
            for (int kh = 0; kh < KS; kh++) {
                const float* yr = y_dec + ((c * HW) + i + kh) * HW + j;
                const float* wk = wr + (c * KS + kh) * KS;
#pragma unroll
                for (int kw = 0; kw < KS; kw++) dot += wk[kw] * yr[kw];
            }
        float corr = (2.0f * (dot - meanX[p] * sumY[i * HO + j]) * (1.0f / (float)PS) + SIG)
                   / (denXa[p] + denYa[i * HO + j] + SIG);
        uint idx = (uint)(i * HO + j);
        pk = ((ull)mono(corr) << 32) | (uint)(~idx);   // first-max tie-break via ~idx
    }
    for (int o = 32; o > 0; o >>= 1) { ull ot = __shfl_down(pk, o); pk = ot > pk ? ot : pk; }
    if (threadIdx.x == 0) atomicMax(&best[p], pk);
}

// ---------------- gather ----------------
__global__ void gather_k(const float* __restrict__ y,
                         const ull* __restrict__ best,
                         float* __restrict__ out) {
    int p = blockIdx.x;
    uint idx = ~((uint)(best[p] & 0xFFFFFFFFull));
    int r = idx / HO, cc = idx - r * HO;
    int pr = p / 20, pc = p - pr * 20;
    for (int e = threadIdx.x; e < PS; e += 256) {
        int c = e / (KS * KS);
        int kh = (e / KS) % KS;
        int kw = e % KS;
        out[c * HW * HW + (pr * KS + kh) * HW + (pc * KS + kw)] =
            y[c * HW * HW + (r + kh) * HW + (cc + kw)];
    }
}

// ---------------- launch ----------------
extern "C" void kernel_launch(void* const* d_in, const int* in_sizes, int n_in,
                              void* d_out, int out_size, void* d_ws, size_t ws_size,
                              hipStream_t stream) {
    const float* x_dec = (const float*)d_in[0];
    const float* y_dec = (const float*)d_in[1];
    const float* y     = (const float*)d_in[2];
    float* out = (float*)d_out;

    char* ws = (char*)d_ws;
    size_t off = 0;
    auto carve = [&](size_t bytes) -> void* {
        void* p = ws + off;
        off += (bytes + 255) & ~(size_t)255;
        return p;
    };
    float*  Wp    = (float*)carve((size_t)NP * PS * 4);           // 2.77 MB
    ushort* ybf   = (ushort*)carve((size_t)CH * HW * HW * 2);     // 1.38 MB
    ushort* Ap    = (ushort*)carve((size_t)NMT * NST * 512 * 2);  // 1.55 MB
    float*  cs    = (float*)carve((size_t)HO * HW * 4);
    float*  cs2   = (float*)carve((size_t)HO * HW * 4);
    float*  sumY  = (float*)carve((size_t)NPOS * 4);
    float*  denYa = (float*)carve((size_t)NPOS * 4);
    float*  meanX = (float*)carve((size_t)NP * 4);
    float*  denXa = (float*)carve((size_t)NP * 4);
    uint*   table = (uint*)carve((size_t)NP * NGRP * 4);          // 5.89 MB
    uint*   flags = (uint*)carve((size_t)MAXF * 4);
    uint*   cnt   = (uint*)carve(256);
    ull*    best  = (ull*)carve((size_t)NP * 8);

    fat1_k<<<6257, 256, 0, stream>>>(x_dec, y_dec, Wp, ybf, cs, cs2);
    fat2_k<<<4240, 256, 0, stream>>>(Wp, cs, cs2, meanX, denXa, Ap, sumY, denYa, cnt, best);

    dim3 grid(8, NIY, 7);
    corr1_k<<<grid, 256, 0, stream>>>(ybf, Ap, meanX, denXa, sumY, denYa, table);

    flag_k<<<NP, 256, 0, stream>>>(table, flags, cnt);
    rescore_k<<<MAXF, 64, 0, stream>>>(Wp, y_dec, meanX, denXa, sumY, denYa, flags, cnt, best);

    gather_k<<<NP, 256, 0, stream>>>(y, best, out);
}